// Round 1
// baseline (286.359 us; speedup 1.0000x reference)
//
#include <hip/hip_runtime.h>
#include <math.h>

#define BB 256
#define NN 1000
#define DD 128
#define HH 8
#define DHH 16
#define NEG -1e9f

// ---------------------------------------------------------------------------
// mask dtype detection: 0 = bool (1 byte), 1 = int32, 2 = float32
// ---------------------------------------------------------------------------
__global__ void k_detect(const unsigned int* mask_words, int* flag) {
    if (threadIdx.x == 0) {
        int all_int = 1, all_float = 1;
        for (int i = 0; i < 256; ++i) {
            unsigned int w = mask_words[i];
            if (!(w == 0u || w == 1u)) all_int = 0;
            if (!(w == 0u || w == 0x3F800000u)) all_float = 0;
        }
        *flag = all_int ? 1 : (all_float ? 2 : 0);
    }
}

__device__ __forceinline__ bool get_mask(const void* m, int flag, size_t idx) {
    if (flag == 1) return ((const int*)m)[idx] != 0;
    if (flag == 2) return ((const float*)m)[idx] != 0.0f;
    return ((const unsigned char*)m)[idx] != 0;
}

// ---------------------------------------------------------------------------
// kernel 1: partial sums over N for the graph-embedding mean
// grid (B, 4), block 256 = 32 float4-cols x 8 n-stripes
// ---------------------------------------------------------------------------
__global__ __launch_bounds__(256) void k_mean(const float* __restrict__ X,
                                              float* __restrict__ partial) {
    int b = blockIdx.x, c = blockIdx.y;
    int col = threadIdx.x & 31;   // float4 column
    int s   = threadIdx.x >> 5;   // stripe
    const float4* Xr = (const float4*)(X + (size_t)b * NN * DD);
    float4 acc = make_float4(0.f, 0.f, 0.f, 0.f);
    int n0 = c * 250, n1 = n0 + 250;
    for (int n = n0 + s; n < n1; n += 8) {
        float4 v = Xr[n * 32 + col];
        acc.x += v.x; acc.y += v.y; acc.z += v.z; acc.w += v.w;
    }
    __shared__ float4 red[8][32];
    red[s][col] = acc;
    __syncthreads();
    for (int st = 4; st >= 1; st >>= 1) {
        if (s < st) {
            float4 o = red[s + st][col];
            red[s][col].x += o.x; red[s][col].y += o.y;
            red[s][col].z += o.z; red[s][col].w += o.w;
        }
        __syncthreads();
    }
    if (s == 0) {
        float4 r = red[0][col];
        float* out = partial + ((size_t)c * BB + b) * DD + col * 4;
        out[0] = r.x; out[1] = r.y; out[2] = r.z; out[3] = r.w;
    }
}

// ---------------------------------------------------------------------------
// kernel 2: graph embed -> fixed context -> query -> qk vectors (per b)
// grid B, block 128 (one thread per d)
// ---------------------------------------------------------------------------
__global__ __launch_bounds__(128) void k_query(
        const float* __restrict__ X, const float* __restrict__ Wfix,
        const float* __restrict__ Wstep, const float* __restrict__ Wnode,
        const float* __restrict__ partial, const int* __restrict__ prev,
        const int* __restrict__ first, float* __restrict__ qk) {
    int b = blockIdx.x, d = threadIdx.x;
    __shared__ float ge[DD], sc[2 * DD], q[DD];
    float g = 0.f;
    for (int c = 0; c < 4; ++c) g += partial[((size_t)c * BB + b) * DD + d];
    ge[d] = g * (1.0f / NN);
    int fi = first[b], pi = prev[b];
    sc[d]      = X[(size_t)b * NN * DD + (size_t)fi * DD + d];
    sc[DD + d] = X[(size_t)b * NN * DD + (size_t)pi * DD + d];
    __syncthreads();
    float acc = 0.f;
    #pragma unroll 4
    for (int k = 0; k < DD; ++k)     acc += ge[k] * Wfix[k * DD + d];
    #pragma unroll 4
    for (int k = 0; k < 2 * DD; ++k) acc += sc[k] * Wstep[k * DD + d];
    q[d] = acc;
    __syncthreads();
    // qk[b,h,d] = (1/sqrt(DH)) * sum_j q[h*DH+j] * Wnode[d, h*DH+j]
    for (int h = 0; h < HH; ++h) {
        float a = 0.f;
        #pragma unroll
        for (int j = 0; j < DHH; ++j)
            a += q[h * DHH + j] * Wnode[(size_t)d * (3 * DD) + h * DHH + j];
        qk[((size_t)b * HH + h) * DD + d] = 0.25f * a;   // 1/sqrt(16)
    }
}

// ---------------------------------------------------------------------------
// kernel 3: fused compat -> masked softmax -> xattn = attn @ X   (per b)
// grid B, block 256
// ---------------------------------------------------------------------------
__global__ __launch_bounds__(256) void k_attn(
        const float* __restrict__ X, const float* __restrict__ qk,
        const void* __restrict__ mask, const int* __restrict__ flag,
        float* __restrict__ xattn) {
    int b = blockIdx.x, tid = threadIdx.x;
    __shared__ float qkl[HH][DD];        // 4 KB
    __shared__ float cm[HH][NN];         // 32 KB  (compat, then attn in place)
    __shared__ float red[HH][32];        // 1 KB
    __shared__ float xp[2][HH][DD];      // 8 KB
    int f = *flag;
    for (int i = tid; i < HH * DD; i += 256) qkl[i / DD][i % DD] = qk[(size_t)b * HH * DD + i];
    __syncthreads();
    const float* Xb = X + (size_t)b * NN * DD;

    // ---- phase A: compat[h][n] ----
    for (int n = tid; n < NN; n += 256) {
        float acc[HH] = {0.f, 0.f, 0.f, 0.f, 0.f, 0.f, 0.f, 0.f};
        const float4* xr = (const float4*)(Xb + (size_t)n * DD);
        #pragma unroll 8
        for (int k = 0; k < 32; ++k) {
            float4 v = xr[k];
            #pragma unroll
            for (int h = 0; h < HH; ++h) {
                acc[h] += v.x * qkl[h][4 * k]     + v.y * qkl[h][4 * k + 1]
                        + v.z * qkl[h][4 * k + 2] + v.w * qkl[h][4 * k + 3];
            }
        }
        bool mk = get_mask(mask, f, (size_t)b * NN + n);
        #pragma unroll
        for (int h = 0; h < HH; ++h) cm[h][n] = mk ? NEG : acc[h];
    }
    __syncthreads();

    // ---- phase B: softmax per h (32 threads per h) ----
    int h = tid >> 5, lane = tid & 31;
    float mx = -INFINITY;
    for (int n = lane; n < NN; n += 32) mx = fmaxf(mx, cm[h][n]);
    red[h][lane] = mx;
    __syncthreads();
    for (int st = 16; st >= 1; st >>= 1) {
        if (lane < st) red[h][lane] = fmaxf(red[h][lane], red[h][lane + st]);
        __syncthreads();
    }
    float m_h = red[h][0];
    __syncthreads();
    float sm = 0.f;
    for (int n = lane; n < NN; n += 32) sm += expf(cm[h][n] - m_h);
    red[h][lane] = sm;
    __syncthreads();
    for (int st = 16; st >= 1; st >>= 1) {
        if (lane < st) red[h][lane] += red[h][lane + st];
        __syncthreads();
    }
    float inv = 1.0f / red[h][0];
    for (int n = lane; n < NN; n += 32) cm[h][n] = expf(cm[h][n] - m_h) * inv;
    __syncthreads();

    // ---- phase C: xattn[h][d] = sum_n attn[h][n] * X[n][d] ----
    int s2 = tid >> 7, d = tid & 127;
    float acc[HH] = {0.f, 0.f, 0.f, 0.f, 0.f, 0.f, 0.f, 0.f};
    for (int n = s2; n < NN; n += 2) {
        float x = Xb[(size_t)n * DD + d];
        #pragma unroll
        for (int hh = 0; hh < HH; ++hh) acc[hh] += cm[hh][n] * x;
    }
    #pragma unroll
    for (int hh = 0; hh < HH; ++hh) xp[s2][hh][d] = acc[hh];
    __syncthreads();
    if (s2 == 0) {
        #pragma unroll
        for (int hh = 0; hh < HH; ++hh)
            xattn[((size_t)b * HH + hh) * DD + d] = xp[0][hh][d] + xp[1][hh][d];
    }
}

// ---------------------------------------------------------------------------
// kernel 4: heads -> glimpse -> gq (per b). grid B, block 128
// ---------------------------------------------------------------------------
__global__ __launch_bounds__(128) void k_out(
        const float* __restrict__ Wnode, const float* __restrict__ Wout,
        const float* __restrict__ xattn, float* __restrict__ gq) {
    int b = blockIdx.x, t = threadIdx.x;
    __shared__ float xa[HH * DD], hd[DD], gl[DD];
    for (int i = t; i < HH * DD; i += 128) xa[i] = xattn[(size_t)b * HH * DD + i];
    __syncthreads();
    int h = t >> 4, j = t & 15;
    float a = 0.f;
    #pragma unroll 4
    for (int d = 0; d < DD; ++d)
        a += xa[h * DD + d] * Wnode[(size_t)d * 384 + DD + h * DHH + j];
    hd[t] = a;                            // t == h*16+j (heads flattened)
    __syncthreads();
    float g = 0.f;
    #pragma unroll 4
    for (int k = 0; k < DD; ++k) g += hd[k] * Wout[(size_t)k * DD + t];
    gl[t] = g;
    __syncthreads();
    float q = 0.f;
    #pragma unroll 4
    for (int k = 0; k < DD; ++k) q += Wnode[(size_t)t * 384 + 2 * DD + k] * gl[k];
    gq[(size_t)b * DD + t] = q * 0.08838834764831845f;   // 1/sqrt(128)
}

// ---------------------------------------------------------------------------
// kernel 5: logits -> tanh clip -> mask -> log_softmax -> out. grid B, block 256
// ---------------------------------------------------------------------------
__global__ __launch_bounds__(256) void k_logits(
        const float* __restrict__ X, const float* __restrict__ gq,
        const void* __restrict__ mask, const int* __restrict__ flag,
        float* __restrict__ out) {
    int b = blockIdx.x, tid = threadIdx.x;
    __shared__ float gql[DD];
    __shared__ float lg[NN];
    __shared__ float red[256];
    int f = *flag;
    if (tid < DD) gql[tid] = gq[(size_t)b * DD + tid];
    __syncthreads();
    const float* Xb = X + (size_t)b * NN * DD;
    for (int n = tid; n < NN; n += 256) {
        const float4* xr = (const float4*)(Xb + (size_t)n * DD);
        float acc = 0.f;
        #pragma unroll 8
        for (int k = 0; k < 32; ++k) {
            float4 v = xr[k];
            acc += v.x * gql[4 * k]     + v.y * gql[4 * k + 1]
                 + v.z * gql[4 * k + 2] + v.w * gql[4 * k + 3];
        }
        float lgt = 10.0f * tanhf(acc);
        lg[n] = get_mask(mask, f, (size_t)b * NN + n) ? NEG : lgt;
    }
    __syncthreads();
    float mx = -INFINITY;
    for (int n = tid; n < NN; n += 256) mx = fmaxf(mx, lg[n]);
    red[tid] = mx;
    __syncthreads();
    for (int st = 128; st >= 1; st >>= 1) {
        if (tid < st) red[tid] = fmaxf(red[tid], red[tid + st]);
        __syncthreads();
    }
    float m = red[0];
    __syncthreads();
    float sm = 0.f;
    for (int n = tid; n < NN; n += 256) sm += expf(lg[n] - m);
    red[tid] = sm;
    __syncthreads();
    for (int st = 128; st >= 1; st >>= 1) {
        if (tid < st) red[tid] += red[tid + st];
        __syncthreads();
    }
    float lse = m + logf(red[0]);
    __syncthreads();
    for (int n = tid; n < NN; n += 256) out[(size_t)b * NN + n] = lg[n] - lse;
}

// ---------------------------------------------------------------------------
extern "C" void kernel_launch(void* const* d_in, const int* in_sizes, int n_in,
                              void* d_out, int out_size, void* d_ws, size_t ws_size,
                              hipStream_t stream) {
    const float* X     = (const float*)d_in[0];
    const float* Wnode = (const float*)d_in[1];
    const float* Wfix  = (const float*)d_in[2];
    const float* Wstep = (const float*)d_in[3];
    const float* Wout  = (const float*)d_in[4];
    const int*   prev  = (const int*)d_in[5];
    const int*   first = (const int*)d_in[6];
    const void*  mask  = d_in[7];
    float* out = (float*)d_out;

    int*   flag    = (int*)d_ws;
    float* w       = (float*)d_ws;
    float* partial = w + 16;                       // 4*B*D
    float* qk      = partial + 4 * BB * DD;        // B*H*D
    float* xattn   = qk + BB * HH * DD;            // B*H*D
    float* gq      = xattn + BB * HH * DD;         // B*D

    k_detect<<<1, 64, 0, stream>>>((const unsigned int*)mask, flag);
    k_mean  <<<dim3(BB, 4), 256, 0, stream>>>(X, partial);
    k_query <<<BB, 128, 0, stream>>>(X, Wfix, Wstep, Wnode, partial, prev, first, qk);
    k_attn  <<<BB, 256, 0, stream>>>(X, qk, mask, flag, xattn);
    k_out   <<<BB, 128, 0, stream>>>(Wnode, Wout, xattn, gq);
    k_logits<<<BB, 256, 0, stream>>>(X, gq, mask, flag, out);
}

// Round 2
// 172.326 us; speedup vs baseline: 1.6617x; 1.6617x over previous
//
#include <hip/hip_runtime.h>
#include <math.h>

#define BB 256
#define NN 1000
#define DD 128
#define HH 8
#define DHH 16
#define NEG -1e9f

// ---------------------------------------------------------------------------
// mask dtype detection: 0 = bool (1 byte), 1 = int32, 2 = float32
// 64 lanes x 4 words each, combined with __all (wave64).
// ---------------------------------------------------------------------------
__global__ void k_detect(const unsigned int* mask_words, int* flag) {
    int i = threadIdx.x;
    unsigned int a = mask_words[i];
    unsigned int b = mask_words[i + 64];
    unsigned int c = mask_words[i + 128];
    unsigned int d = mask_words[i + 192];
    int ii = (a <= 1u) && (b <= 1u) && (c <= 1u) && (d <= 1u);
    int ff = (a == 0u || a == 0x3F800000u) && (b == 0u || b == 0x3F800000u) &&
             (c == 0u || c == 0x3F800000u) && (d == 0u || d == 0x3F800000u);
    int all_int = __all(ii);
    int all_float = __all(ff);
    if (threadIdx.x == 0) *flag = all_int ? 1 : (all_float ? 2 : 0);
}

__device__ __forceinline__ bool get_mask(const void* m, int flag, size_t idx) {
    if (flag == 1) return ((const int*)m)[idx] != 0;
    if (flag == 2) return ((const float*)m)[idx] != 0.0f;
    return ((const unsigned char*)m)[idx] != 0;
}

// ---------------------------------------------------------------------------
// kernel 1: partial sums over N for the graph-embedding mean
// grid (B, 4), block 256 = 32 float4-cols x 8 n-stripes
// ---------------------------------------------------------------------------
__global__ __launch_bounds__(256) void k_mean(const float* __restrict__ X,
                                              float* __restrict__ partial) {
    int b = blockIdx.x, c = blockIdx.y;
    int col = threadIdx.x & 31;   // float4 column
    int s   = threadIdx.x >> 5;   // stripe
    const float4* Xr = (const float4*)(X + (size_t)b * NN * DD);
    float4 acc = make_float4(0.f, 0.f, 0.f, 0.f);
    int n0 = c * 250, n1 = n0 + 250;
    for (int n = n0 + s; n < n1; n += 8) {
        float4 v = Xr[n * 32 + col];
        acc.x += v.x; acc.y += v.y; acc.z += v.z; acc.w += v.w;
    }
    __shared__ float4 red[8][32];
    red[s][col] = acc;
    __syncthreads();
    for (int st = 4; st >= 1; st >>= 1) {
        if (s < st) {
            float4 o = red[s + st][col];
            red[s][col].x += o.x; red[s][col].y += o.y;
            red[s][col].z += o.z; red[s][col].w += o.w;
        }
        __syncthreads();
    }
    if (s == 0) {
        float4 r = red[0][col];
        float* out = partial + ((size_t)c * BB + b) * DD + col * 4;
        out[0] = r.x; out[1] = r.y; out[2] = r.z; out[3] = r.w;
    }
}

// ---------------------------------------------------------------------------
// kernel 2: graph embed -> fixed context -> query -> qk vectors
// grid B/2, block 256: two batch elements per block (sub-block = tid>>7)
// ---------------------------------------------------------------------------
__global__ __launch_bounds__(256) void k_query(
        const float* __restrict__ X, const float* __restrict__ Wfix,
        const float* __restrict__ Wstep, const float* __restrict__ Wnode,
        const float* __restrict__ partial, const int* __restrict__ prev,
        const int* __restrict__ first, float* __restrict__ qk) {
    int sb = threadIdx.x >> 7, d = threadIdx.x & 127;
    int b = blockIdx.x * 2 + sb;
    __shared__ float ge[2][DD], sc[2][2 * DD], q[2][DD];
    float g = 0.f;
    for (int c = 0; c < 4; ++c) g += partial[((size_t)c * BB + b) * DD + d];
    ge[sb][d] = g * (1.0f / NN);
    int fi = first[b], pi = prev[b];
    sc[sb][d]      = X[(size_t)b * NN * DD + (size_t)fi * DD + d];
    sc[sb][DD + d] = X[(size_t)b * NN * DD + (size_t)pi * DD + d];
    __syncthreads();
    float acc = 0.f;
    #pragma unroll 4
    for (int k = 0; k < DD; ++k)     acc += ge[sb][k] * Wfix[k * DD + d];
    #pragma unroll 4
    for (int k = 0; k < 2 * DD; ++k) acc += sc[sb][k] * Wstep[k * DD + d];
    q[sb][d] = acc;
    __syncthreads();
    // qk[b,h,d] = (1/sqrt(DH)) * sum_j q[h*DH+j] * Wnode[d, h*DH+j]
    for (int h = 0; h < HH; ++h) {
        float a = 0.f;
        #pragma unroll
        for (int j = 0; j < DHH; ++j)
            a += q[sb][h * DHH + j] * Wnode[(size_t)d * (3 * DD) + h * DHH + j];
        qk[((size_t)b * HH + h) * DD + d] = 0.25f * a;   // 1/sqrt(16)
    }
}

// ---------------------------------------------------------------------------
// kernel 3: fused compat -> masked softmax -> xattn = attn @ X   (per b)
// grid B, block 1024 (16 waves/CU)
// ---------------------------------------------------------------------------
__global__ __launch_bounds__(1024) void k_attn(
        const float* __restrict__ X, const float* __restrict__ qk,
        const void* __restrict__ mask, const int* __restrict__ flag,
        float* __restrict__ xattn) {
    int b = blockIdx.x, tid = threadIdx.x;
    __shared__ float qkl[HH][DD];        // 4 KB
    __shared__ float cm[HH][1024];       // 32 KB (compat -> attn -> xp scratch)
    __shared__ float red[16];
    int f = *flag;
    for (int i = tid; i < HH * DD; i += 1024) qkl[i >> 7][i & 127] = qk[(size_t)b * HH * DD + i];
    __syncthreads();
    const float* Xb = X + (size_t)b * NN * DD;

    // ---- phase A: compat[h][n], one n-row per thread ----
    if (tid < NN) {
        int n = tid;
        float acc[HH] = {0.f, 0.f, 0.f, 0.f, 0.f, 0.f, 0.f, 0.f};
        const float4* xr = (const float4*)(Xb + (size_t)n * DD);
        #pragma unroll 8
        for (int k = 0; k < 32; ++k) {
            float4 v = xr[k];
            #pragma unroll
            for (int h = 0; h < HH; ++h) {
                acc[h] += v.x * qkl[h][4 * k]     + v.y * qkl[h][4 * k + 1]
                        + v.z * qkl[h][4 * k + 2] + v.w * qkl[h][4 * k + 3];
            }
        }
        bool mk = get_mask(mask, f, (size_t)b * NN + n);
        #pragma unroll
        for (int h = 0; h < HH; ++h) cm[h][n] = mk ? NEG : acc[h];
    }
    __syncthreads();

    // ---- phase B: softmax per h (128 threads per h: 2 waves) ----
    int h = tid >> 7, lane = tid & 127;
    float mx = -INFINITY;
    for (int n = lane; n < NN; n += 128) mx = fmaxf(mx, cm[h][n]);
    #pragma unroll
    for (int off = 32; off >= 1; off >>= 1) mx = fmaxf(mx, __shfl_xor(mx, off, 64));
    if ((tid & 63) == 0) red[tid >> 6] = mx;   // tid>>6 == h*2 + subwave
    __syncthreads();
    float m_h = fmaxf(red[h * 2], red[h * 2 + 1]);
    __syncthreads();
    float sm = 0.f;
    for (int n = lane; n < NN; n += 128) {
        float p = expf(cm[h][n] - m_h);
        cm[h][n] = p;
        sm += p;
    }
    #pragma unroll
    for (int off = 32; off >= 1; off >>= 1) sm += __shfl_xor(sm, off, 64);
    if ((tid & 63) == 0) red[tid >> 6] = sm;
    __syncthreads();
    float inv = 1.0f / (red[h * 2] + red[h * 2 + 1]);
    for (int n = lane; n < NN; n += 128) cm[h][n] *= inv;
    __syncthreads();

    // ---- phase C: xattn[h][d] = sum_n attn[h][n] * X[n][d], 8 n-stripes ----
    int s2 = tid >> 7, d = tid & 127;
    float acc[HH] = {0.f, 0.f, 0.f, 0.f, 0.f, 0.f, 0.f, 0.f};
    for (int n = s2; n < NN; n += 8) {
        float x = Xb[(size_t)n * DD + d];
        #pragma unroll
        for (int hh = 0; hh < HH; ++hh) acc[hh] += cm[hh][n] * x;
    }
    __syncthreads();                       // everyone done READING cm
    float* xp = &cm[0][0];                 // reuse as [8 stripes][8 h][128 d]
    #pragma unroll
    for (int hh = 0; hh < HH; ++hh) xp[((size_t)s2 * HH + hh) * DD + d] = acc[hh];
    __syncthreads();
    if (s2 == 0) {
        #pragma unroll
        for (int hh = 0; hh < HH; ++hh) {
            float s = 0.f;
            #pragma unroll
            for (int st = 0; st < 8; ++st) s += xp[((size_t)st * HH + hh) * DD + d];
            xattn[((size_t)b * HH + hh) * DD + d] = s;
        }
    }
}

// ---------------------------------------------------------------------------
// kernel 4: heads -> glimpse -> gq. grid B/2, block 256 (2 b per block)
// ---------------------------------------------------------------------------
__global__ __launch_bounds__(256) void k_out(
        const float* __restrict__ Wnode, const float* __restrict__ Wout,
        const float* __restrict__ xattn, float* __restrict__ gq) {
    int sb = threadIdx.x >> 7, t = threadIdx.x & 127;
    int b = blockIdx.x * 2 + sb;
    __shared__ float xa[2][HH * DD], hd[2][DD], gl[2][DD];
    for (int i = t; i < HH * DD; i += 128) xa[sb][i] = xattn[(size_t)b * HH * DD + i];
    __syncthreads();
    int h = t >> 4, j = t & 15;
    float a = 0.f;
    #pragma unroll 4
    for (int d = 0; d < DD; ++d)
        a += xa[sb][h * DD + d] * Wnode[(size_t)d * 384 + DD + h * DHH + j];
    hd[sb][t] = a;                         // t == h*16+j (heads flattened)
    __syncthreads();
    float g = 0.f;
    #pragma unroll 4
    for (int k = 0; k < DD; ++k) g += hd[sb][k] * Wout[(size_t)k * DD + t];
    gl[sb][t] = g;
    __syncthreads();
    float q = 0.f;
    #pragma unroll 4
    for (int k = 0; k < DD; ++k) q += Wnode[(size_t)t * 384 + 2 * DD + k] * gl[sb][k];
    gq[(size_t)b * DD + t] = q * 0.08838834764831845f;   // 1/sqrt(128)
}

// ---------------------------------------------------------------------------
// kernel 5: logits -> tanh clip -> mask -> log_softmax -> out.
// grid B, block 1024, one n-row per thread, logits kept in registers.
// ---------------------------------------------------------------------------
__global__ __launch_bounds__(1024) void k_logits(
        const float* __restrict__ X, const float* __restrict__ gq,
        const void* __restrict__ mask, const int* __restrict__ flag,
        float* __restrict__ out) {
    int b = blockIdx.x, tid = threadIdx.x;
    __shared__ float gql[DD];
    __shared__ float red[16];
    int f = *flag;
    if (tid < DD) gql[tid] = gq[(size_t)b * DD + tid];
    __syncthreads();
    const float* Xb = X + (size_t)b * NN * DD;
    float v = -INFINITY;
    if (tid < NN) {
        const float4* xr = (const float4*)(Xb + (size_t)tid * DD);
        float acc = 0.f;
        #pragma unroll 8
        for (int k = 0; k < 32; ++k) {
            float4 x = xr[k];
            acc += x.x * gql[4 * k]     + x.y * gql[4 * k + 1]
                 + x.z * gql[4 * k + 2] + x.w * gql[4 * k + 3];
        }
        float lgt = 10.0f * tanhf(acc);
        v = get_mask(mask, f, (size_t)b * NN + tid) ? NEG : lgt;
    }
    // block max
    float mx = v;
    #pragma unroll
    for (int off = 32; off >= 1; off >>= 1) mx = fmaxf(mx, __shfl_xor(mx, off, 64));
    if ((tid & 63) == 0) red[tid >> 6] = mx;
    __syncthreads();
    float m = -INFINITY;
    #pragma unroll
    for (int w = 0; w < 16; ++w) m = fmaxf(m, red[w]);
    __syncthreads();
    // block sum of exp
    float e = (tid < NN) ? expf(v - m) : 0.f;
    float sm = e;
    #pragma unroll
    for (int off = 32; off >= 1; off >>= 1) sm += __shfl_xor(sm, off, 64);
    if ((tid & 63) == 0) red[tid >> 6] = sm;
    __syncthreads();
    float s = 0.f;
    #pragma unroll
    for (int w = 0; w < 16; ++w) s += red[w];
    float lse = m + logf(s);
    if (tid < NN) out[(size_t)b * NN + tid] = v - lse;
}

// ---------------------------------------------------------------------------
extern "C" void kernel_launch(void* const* d_in, const int* in_sizes, int n_in,
                              void* d_out, int out_size, void* d_ws, size_t ws_size,
                              hipStream_t stream) {
    const float* X     = (const float*)d_in[0];
    const float* Wnode = (const float*)d_in[1];
    const float* Wfix  = (const float*)d_in[2];
    const float* Wstep = (const float*)d_in[3];
    const float* Wout  = (const float*)d_in[4];
    const int*   prev  = (const int*)d_in[5];
    const int*   first = (const int*)d_in[6];
    const void*  mask  = d_in[7];
    float* out = (float*)d_out;

    int*   flag    = (int*)d_ws;
    float* w       = (float*)d_ws;
    float* partial = w + 16;                       // 4*B*D
    float* qk      = partial + 4 * BB * DD;        // B*H*D
    float* xattn   = qk + BB * HH * DD;            // B*H*D
    float* gq      = xattn + BB * HH * DD;         // B*D

    k_detect<<<1, 64, 0, stream>>>((const unsigned int*)mask, flag);
    k_mean  <<<dim3(BB, 4), 256, 0, stream>>>(X, partial);
    k_query <<<BB / 2, 256, 0, stream>>>(X, Wfix, Wstep, Wnode, partial, prev, first, qk);
    k_attn  <<<BB, 1024, 0, stream>>>(X, qk, mask, flag, xattn);
    k_out   <<<BB / 2, 256, 0, stream>>>(Wnode, Wout, xattn, gq);
    k_logits<<<BB, 1024, 0, stream>>>(X, gq, mask, flag, out);
}

// Round 3
// 109.392 us; speedup vs baseline: 2.6177x; 1.5753x over previous
//
#include <hip/hip_runtime.h>
#include <math.h>

#define BB 256
#define NN 1000
#define DD 128
#define HH 8
#define NEG -1e9f

__device__ __forceinline__ float bf2f(unsigned int u) {
    return __uint_as_float(u << 16);
}
__device__ __forceinline__ unsigned short f2bf(float f) {
    unsigned int u = __float_as_uint(f);
    u += 0x7FFFu + ((u >> 16) & 1u);          // RNE
    return (unsigned short)(u >> 16);
}
__device__ __forceinline__ bool get_mask(const void* m, int flag, size_t idx) {
    if (flag == 1) return ((const int*)m)[idx] != 0;
    if (flag == 2) return ((const float*)m)[idx] != 0.0f;
    return ((const unsigned char*)m)[idx] != 0;
}

// ---------------------------------------------------------------------------
// One block per batch element. Phases:
//  -1: mask dtype detect (wave 0) + step-context row loads (threads 256..511)
//   0: mean over X[b] (+ bf16 downconvert of X[b] into workspace)
//  0b: query q = Wfix^T ge + Wstep^T sc ; qk[h][d] (compat key vectors)
//   A: compat[h][n] = X[n]·qk[h]      (8 lanes per row, coalesced)
//   B: masked softmax per head (unnormalized p; 1/sum saved to invh)
//   C: xattn[h][d] = invh[h] * sum_n p[h][n] X[n][d]
//   D: heads -> glimpse -> gq (split-8 GEMVs + LDS reduce)
//   E: logits = X[n]·gq, tanh clip, mask, block log-softmax, store
// ---------------------------------------------------------------------------
template<int BF16>
__global__ __launch_bounds__(1024) void k_fused(
        const float* __restrict__ X, const float* __restrict__ Wnode,
        const float* __restrict__ Wfix, const float* __restrict__ Wstep,
        const float* __restrict__ Wout, const int* __restrict__ prev,
        const int* __restrict__ first, const void* __restrict__ mask,
        unsigned short* __restrict__ Xb, float* __restrict__ out) {
    int b = blockIdx.x, tid = threadIdx.x;

    __shared__ __align__(16) float cm[HH * 1024];   // 32KB: red4 / compat / xp
    __shared__ __align__(16) float qkl[HH * DD];    // 4KB : qk vectors, later lg
    __shared__ __align__(16) float qpart[8 * DD];   // 4KB : split-k scratch
    __shared__ float xa[HH * DD];                   // 4KB : xattn
    __shared__ float ge[DD], q[DD], sc[2 * DD], hd[DD], gl[DD], gqv[DD];
    __shared__ float red[16], invh[8];
    __shared__ int s_flag;

    const size_t xoff = (size_t)b * NN * DD;

    // ---- phase -1 ----
    if (tid < 64) {
        const unsigned int* mw = (const unsigned int*)mask;
        unsigned int a0 = mw[tid], a1 = mw[tid + 64], a2 = mw[tid + 128], a3 = mw[tid + 192];
        int ii = (a0 <= 1u) && (a1 <= 1u) && (a2 <= 1u) && (a3 <= 1u);
        int ff = (a0 == 0u || a0 == 0x3F800000u) && (a1 == 0u || a1 == 0x3F800000u) &&
                 (a2 == 0u || a2 == 0x3F800000u) && (a3 == 0u || a3 == 0x3F800000u);
        int ai = __all(ii), af = __all(ff);
        if (tid == 0) s_flag = ai ? 1 : (af ? 2 : 0);
    }
    if (tid >= 256 && tid < 512) {
        int t = tid - 256;
        int src = (t < DD) ? first[b] : prev[b];
        sc[t] = X[xoff + (size_t)src * DD + (t & 127)];
    }

    // ---- phase 0: mean (+ bf16 store) ----
    {
        float4* red4 = (float4*)cm;                 // [32][32]
        int c = tid & 31, s = tid >> 5;
        const float4* Xr = (const float4*)(X + xoff);
        float4 acc = make_float4(0.f, 0.f, 0.f, 0.f);
        for (int n = s; n < NN; n += 32) {
            float4 v = Xr[n * 32 + c];
            acc.x += v.x; acc.y += v.y; acc.z += v.z; acc.w += v.w;
            if (BF16) {
                uint2 p;
                p.x = (unsigned)f2bf(v.x) | ((unsigned)f2bf(v.y) << 16);
                p.y = (unsigned)f2bf(v.z) | ((unsigned)f2bf(v.w) << 16);
                ((uint2*)Xb)[(size_t)b * NN * 32 + n * 32 + c] = p;
            }
        }
        red4[s * 32 + c] = acc;
        __syncthreads();
        for (int st = 16; st >= 1; st >>= 1) {
            if (s < st) {
                float4 o = red4[(s + st) * 32 + c];
                float4 r = red4[s * 32 + c];
                r.x += o.x; r.y += o.y; r.z += o.z; r.w += o.w;
                red4[s * 32 + c] = r;
            }
            __syncthreads();
        }
        if (s == 0) {
            float4 r = red4[c];
            ge[4 * c]     = r.x * (1.0f / NN);
            ge[4 * c + 1] = r.y * (1.0f / NN);
            ge[4 * c + 2] = r.z * (1.0f / NN);
            ge[4 * c + 3] = r.w * (1.0f / NN);
        }
        __syncthreads();
    }
    const int flag = s_flag;

    // ---- phase 0b: query + qk ----
    {
        int p = tid >> 7, d = tid & 127;
        float a = 0.f;
        #pragma unroll 4
        for (int k = p * 16; k < p * 16 + 16; ++k) a += ge[k] * Wfix[(size_t)k * DD + d];
        #pragma unroll 4
        for (int k = p * 32; k < p * 32 + 32; ++k) a += sc[k] * Wstep[(size_t)k * DD + d];
        qpart[p * DD + d] = a;
        __syncthreads();
        if (tid < DD) {
            float s = 0.f;
            #pragma unroll
            for (int pp = 0; pp < 8; ++pp) s += qpart[pp * DD + tid];
            q[tid] = s;
        }
        __syncthreads();
        int d2 = tid >> 3, h = tid & 7;
        const float4* wr = (const float4*)(Wnode + (size_t)d2 * 384 + h * 16);
        float a2 = 0.f;
        #pragma unroll
        for (int j4 = 0; j4 < 4; ++j4) {
            float4 w = wr[j4];
            a2 += w.x * q[h * 16 + 4 * j4]     + w.y * q[h * 16 + 4 * j4 + 1]
                + w.z * q[h * 16 + 4 * j4 + 2] + w.w * q[h * 16 + 4 * j4 + 3];
        }
        qkl[h * DD + d2] = 0.25f * a2;              // 1/sqrt(16)
        __syncthreads();
    }

    // ---- phase A: compat ----
    {
        int g = tid & 7;
        for (int it = 0; it < 8; ++it) {
            int n = it * 128 + (tid >> 3);
            if (n < NN) {
                float acc[HH] = {0.f, 0.f, 0.f, 0.f, 0.f, 0.f, 0.f, 0.f};
                if (BF16) {
                    const uint4* xr = (const uint4*)(Xb + xoff + (size_t)n * DD);
                    uint4 c0 = xr[g], c1 = xr[g + 8];
                    unsigned int wsv[8] = {c0.x, c0.y, c0.z, c0.w, c1.x, c1.y, c1.z, c1.w};
                    #pragma unroll
                    for (int i = 0; i < 8; ++i) {
                        int col = (i < 4) ? (8 * g + 2 * i) : (64 + 8 * g + 2 * (i - 4));
                        float lo = bf2f(wsv[i] & 0xffffu), hi = bf2f(wsv[i] >> 16);
                        #pragma unroll
                        for (int h = 0; h < HH; ++h)
                            acc[h] += lo * qkl[h * DD + col] + hi * qkl[h * DD + col + 1];
                    }
                } else {
                    const float4* xr = (const float4*)(X + xoff + (size_t)n * DD);
                    #pragma unroll
                    for (int i = 0; i < 4; ++i) {
                        float4 v = xr[g + 8 * i];
                        int col = 4 * (g + 8 * i);
                        #pragma unroll
                        for (int h = 0; h < HH; ++h)
                            acc[h] += v.x * qkl[h * DD + col]     + v.y * qkl[h * DD + col + 1]
                                    + v.z * qkl[h * DD + col + 2] + v.w * qkl[h * DD + col + 3];
                    }
                }
                #pragma unroll
                for (int h = 0; h < HH; ++h) {
                    acc[h] += __shfl_xor(acc[h], 1, 8);
                    acc[h] += __shfl_xor(acc[h], 2, 8);
                    acc[h] += __shfl_xor(acc[h], 4, 8);
                }
                bool mk = get_mask(mask, flag, (size_t)b * NN + n);
                cm[g * 1024 + n] = mk ? NEG : acc[g];
            }
        }
        __syncthreads();
    }

    // ---- phase B: masked softmax (unnormalized; invh saved) ----
    {
        int h = tid >> 7, lane = tid & 127;
        float mx = -INFINITY;
        for (int n = lane; n < NN; n += 128) mx = fmaxf(mx, cm[h * 1024 + n]);
        #pragma unroll
        for (int off = 32; off >= 1; off >>= 1) mx = fmaxf(mx, __shfl_xor(mx, off, 64));
        if ((tid & 63) == 0) red[tid >> 6] = mx;
        __syncthreads();
        float m_h = fmaxf(red[2 * h], red[2 * h + 1]);
        float sm = 0.f;
        for (int n = lane; n < NN; n += 128) {
            float p = expf(cm[h * 1024 + n] - m_h);
            cm[h * 1024 + n] = p;
            sm += p;
        }
        #pragma unroll
        for (int off = 32; off >= 1; off >>= 1) sm += __shfl_xor(sm, off, 64);
        __syncthreads();                            // red reads done
        if ((tid & 63) == 0) red[tid >> 6] = sm;
        __syncthreads();
        if (tid < HH) invh[tid] = 1.0f / (red[2 * tid] + red[2 * tid + 1]);
        __syncthreads();
    }

    // ---- phase C: xattn ----
    {
        int s = tid >> 7, d = tid & 127;
        float acc[HH] = {0.f, 0.f, 0.f, 0.f, 0.f, 0.f, 0.f, 0.f};
        for (int n = s; n < NN; n += 8) {
            float x = BF16 ? bf2f((unsigned int)Xb[xoff + (size_t)n * DD + d])
                           : X[xoff + (size_t)n * DD + d];
            #pragma unroll
            for (int h = 0; h < HH; ++h) acc[h] += cm[h * 1024 + n] * x;
        }
        __syncthreads();                            // done reading cm
        float* xp = cm;                             // [8 stripes][8 h][128 d]
        #pragma unroll
        for (int h = 0; h < HH; ++h) xp[(s * HH + h) * DD + d] = acc[h];
        __syncthreads();
        if (s == 0) {
            #pragma unroll
            for (int h = 0; h < HH; ++h) {
                float t = 0.f;
                #pragma unroll
                for (int ss = 0; ss < 8; ++ss) t += xp[(ss * HH + h) * DD + d];
                xa[h * DD + d] = t * invh[h];
            }
        }
        __syncthreads();
    }

    // ---- phase D: heads -> glimpse -> gq ----
    {
        int p = tid >> 7, t = tid & 127;
        int h = t >> 4;
        float a = 0.f;
        #pragma unroll 4
        for (int d = p * 16; d < p * 16 + 16; ++d)
            a += xa[h * DD + d] * Wnode[(size_t)d * 384 + 128 + t];
        qpart[p * DD + t] = a;
        __syncthreads();
        if (tid < DD) {
            float s = 0.f;
            #pragma unroll
            for (int pp = 0; pp < 8; ++pp) s += qpart[pp * DD + tid];
            hd[tid] = s;
        }
        __syncthreads();
        a = 0.f;
        #pragma unroll 4
        for (int k = p * 16; k < p * 16 + 16; ++k) a += hd[k] * Wout[(size_t)k * DD + t];
        qpart[p * DD + t] = a;
        __syncthreads();
        if (tid < DD) {
            float s = 0.f;
            #pragma unroll
            for (int pp = 0; pp < 8; ++pp) s += qpart[pp * DD + tid];
            gl[tid] = s;
        }
        __syncthreads();
        const float4* wr = (const float4*)(Wnode + (size_t)t * 384 + 256 + p * 16);
        a = 0.f;
        #pragma unroll
        for (int j4 = 0; j4 < 4; ++j4) {
            float4 w = wr[j4];
            int k = p * 16 + 4 * j4;
            a += w.x * gl[k] + w.y * gl[k + 1] + w.z * gl[k + 2] + w.w * gl[k + 3];
        }
        qpart[p * DD + t] = a;
        __syncthreads();
        if (tid < DD) {
            float s = 0.f;
            #pragma unroll
            for (int pp = 0; pp < 8; ++pp) s += qpart[pp * DD + tid];
            gqv[tid] = s * 0.08838834764831845f;    // 1/sqrt(128)
        }
        __syncthreads();
    }

    // ---- phase E: logits + log-softmax ----
    {
        float* lg = qkl;                            // reuse 4KB
        int g = tid & 7;
        for (int it = 0; it < 8; ++it) {
            int n = it * 128 + (tid >> 3);
            if (n < NN) {
                float a = 0.f;
                if (BF16) {
                    const uint4* xr = (const uint4*)(Xb + xoff + (size_t)n * DD);
                    uint4 c0 = xr[g], c1 = xr[g + 8];
                    unsigned int wsv[8] = {c0.x, c0.y, c0.z, c0.w, c1.x, c1.y, c1.z, c1.w};
                    #pragma unroll
                    for (int i = 0; i < 8; ++i) {
                        int col = (i < 4) ? (8 * g + 2 * i) : (64 + 8 * g + 2 * (i - 4));
                        a += bf2f(wsv[i] & 0xffffu) * gqv[col] + bf2f(wsv[i] >> 16) * gqv[col + 1];
                    }
                } else {
                    const float4* xr = (const float4*)(X + xoff + (size_t)n * DD);
                    #pragma unroll
                    for (int i = 0; i < 4; ++i) {
                        float4 v = xr[g + 8 * i];
                        int col = 4 * (g + 8 * i);
                        a += v.x * gqv[col] + v.y * gqv[col + 1] + v.z * gqv[col + 2] + v.w * gqv[col + 3];
                    }
                }
                a += __shfl_xor(a, 1, 8);
                a += __shfl_xor(a, 2, 8);
                a += __shfl_xor(a, 4, 8);
                if (g == 0) {
                    float lgt = 10.0f * tanhf(a);
                    lg[n] = get_mask(mask, flag, (size_t)b * NN + n) ? NEG : lgt;
                }
            }
        }
        __syncthreads();
        float v = (tid < NN) ? lg[tid] : -INFINITY;
        float mx = v;
        #pragma unroll
        for (int off = 32; off >= 1; off >>= 1) mx = fmaxf(mx, __shfl_xor(mx, off, 64));
        if ((tid & 63) == 0) red[tid >> 6] = mx;
        __syncthreads();
        float m = red[0];
        #pragma unroll
        for (int w = 1; w < 16; ++w) m = fmaxf(m, red[w]);
        float e = (tid < NN) ? expf(v - m) : 0.f;
        float sm = e;
        #pragma unroll
        for (int off = 32; off >= 1; off >>= 1) sm += __shfl_xor(sm, off, 64);
        __syncthreads();                            // red reads done
        if ((tid & 63) == 0) red[tid >> 6] = sm;
        __syncthreads();
        float s2 = 0.f;
        #pragma unroll
        for (int w = 0; w < 16; ++w) s2 += red[w];
        float lse = m + logf(s2);
        if (tid < NN) out[(size_t)b * NN + tid] = v - lse;
    }
}

// ---------------------------------------------------------------------------
extern "C" void kernel_launch(void* const* d_in, const int* in_sizes, int n_in,
                              void* d_out, int out_size, void* d_ws, size_t ws_size,
                              hipStream_t stream) {
    const float* X     = (const float*)d_in[0];
    const float* Wnode = (const float*)d_in[1];
    const float* Wfix  = (const float*)d_in[2];
    const float* Wstep = (const float*)d_in[3];
    const float* Wout  = (const float*)d_in[4];
    const int*   prev  = (const int*)d_in[5];
    const int*   first = (const int*)d_in[6];
    const void*  mask  = d_in[7];
    float* out = (float*)d_out;

    const size_t need = 256 + (size_t)2 * BB * NN * DD;   // bf16 copy of X
    if (ws_size >= need) {
        unsigned short* Xb = (unsigned short*)((char*)d_ws + 256);
        k_fused<1><<<BB, 1024, 0, stream>>>(X, Wnode, Wfix, Wstep, Wout,
                                            prev, first, mask, Xb, out);
    } else {
        k_fused<0><<<BB, 1024, 0, stream>>>(X, Wnode, Wfix, Wstep, Wout,
                                            prev, first, mask, nullptr, out);
    }
}